// Round 1
// baseline (797.813 us; speedup 1.0000x reference)
//
#include <hip/hip_runtime.h>
#include <math.h>

// ResBlock (DGCNN edge-conv) fused pipeline, fp32 throughout.
//
// Refactoring:
//   ranking score s_m = 2<x_n,x_m> - xx[m]           (xx[n] row-constant, dropped)
//   y[b,o,n,k] = U[b,j_k,o] + V[b,n,o],  U = W1 @ X, V = (W2-W1) @ X
//   BN+relu+max_k: out = relu(sc*(sc>=0 ? max_k y : min_k y) + sh) + x
//
// Pipeline: k_xx -> k_knn (fused gram + per-quarter top5) -> k_knn_merge
//           k_uv (U,V GEMMs) -> k_gather (y stats + max/min) -> k_stats -> k_final
//
// B=4, C=256, N=4096, K=5.

#define Bc 4
#define Cc 256
#define Nc 4096

// ---- workspace layout (bytes) ----
#define WS_XX    ((size_t)0)            //  16384 f
#define WS_KNN   ((size_t)65536)        //  81920 i
#define WS_U     ((size_t)393216)       //  4.19M f
#define WS_V     ((size_t)17170432)     //  4.19M f
#define WS_MX    ((size_t)33947648)     //  4.19M f
#define WS_MN    ((size_t)50724864)     //  4.19M f
#define WS_P1    ((size_t)67502080)     //  65536 f
#define WS_P2    ((size_t)67764224)     //  65536 f
#define WS_SCSH  ((size_t)68026368)     //  512 f
#define WS_PVAL  ((size_t)68028416)     //  327680 f
#define WS_PIDX  ((size_t)69339136)     //  327680 i
// total ~67.4 MB

__device__ __forceinline__ void insert5(float (&v)[5], int (&ix)[5], float s, int id) {
  if (s <= v[4]) return;
  if (s > v[0]) {
    v[4]=v[3]; ix[4]=ix[3]; v[3]=v[2]; ix[3]=ix[2];
    v[2]=v[1]; ix[2]=ix[1]; v[1]=v[0]; ix[1]=ix[0];
    v[0]=s; ix[0]=id;
  } else if (s > v[1]) {
    v[4]=v[3]; ix[4]=ix[3]; v[3]=v[2]; ix[3]=ix[2];
    v[2]=v[1]; ix[2]=ix[1]; v[1]=s; ix[1]=id;
  } else if (s > v[2]) {
    v[4]=v[3]; ix[4]=ix[3]; v[3]=v[2]; ix[3]=ix[2];
    v[2]=s; ix[2]=id;
  } else if (s > v[3]) {
    v[4]=v[3]; ix[4]=ix[3]; v[3]=s; ix[3]=id;
  } else {
    v[4]=s; ix[4]=id;
  }
}

// ---- xx[b,n] = sum_c x^2 ----
__global__ __launch_bounds__(256) void k_xx(const float* __restrict__ x,
                                            float* __restrict__ xx) {
  const int g0 = blockIdx.x * 64;           // 256 blocks cover B*N
  const int b = g0 >> 12, n0 = g0 & 4095;
  const int nl = threadIdx.x & 63, cq = threadIdx.x >> 6;
  const float* p = x + ((size_t)(b * Cc + cq * 64)) * Nc + n0 + nl;
  float s = 0.f;
  #pragma unroll 8
  for (int c = 0; c < 64; ++c) { float v = p[(size_t)c * Nc]; s += v * v; }
  __shared__ float sh[4][64];
  sh[cq][nl] = s;
  __syncthreads();
  if (threadIdx.x < 64) {
    xx[g0 + threadIdx.x] = sh[0][threadIdx.x] + sh[1][threadIdx.x]
                         + sh[2][threadIdx.x] + sh[3][threadIdx.x];
  }
}

// ---- fused gram + top5 (per m-quarter). grid (N/64, B, 4) ----
__global__ __launch_bounds__(256) void k_knn(const float* __restrict__ x,
                                             const float* __restrict__ xx,
                                             float* __restrict__ pval,
                                             int* __restrict__ pidx) {
  __shared__ float As[64][64];
  __shared__ float Bs[64][64];
  const int tid = threadIdx.x;
  const int tx = tid & 15, ty = tid >> 4;
  const int n0 = blockIdx.x * 64;
  const int b  = blockIdx.y;
  const int mq = blockIdx.z;
  const float* Xb = x + (size_t)b * Cc * Nc;
  const int i4 = (tid & 15) * 4;
  const int krow = tid >> 4;

  float tv[4][5]; int tix[4][5];
  #pragma unroll
  for (int i = 0; i < 4; ++i)
    #pragma unroll
    for (int q = 0; q < 5; ++q) { tv[i][q] = -INFINITY; tix[i][q] = 0; }

  for (int mt = 0; mt < 16; ++mt) {
    const int m0 = (mq * 16 + mt) * 64;
    float acc[4][4];
    #pragma unroll
    for (int ii = 0; ii < 4; ++ii)
      #pragma unroll
      for (int jj = 0; jj < 4; ++jj) acc[ii][jj] = 0.f;

    for (int kc = 0; kc < 4; ++kc) {
      const int kb = kc * 64;
      #pragma unroll
      for (int it = 0; it < 4; ++it) {
        const int k = krow + 16 * it;
        const size_t rowoff = (size_t)(kb + k) * Nc;
        *(float4*)&As[k][i4] = *(const float4*)(Xb + rowoff + n0 + i4);
        *(float4*)&Bs[k][i4] = *(const float4*)(Xb + rowoff + m0 + i4);
      }
      __syncthreads();
      #pragma unroll 8
      for (int kl = 0; kl < 64; ++kl) {
        const float4 a4 = *(const float4*)&As[kl][ty * 4];
        const float4 b4 = *(const float4*)&Bs[kl][tx * 4];
        const float a[4]  = {a4.x, a4.y, a4.z, a4.w};
        const float bb[4] = {b4.x, b4.y, b4.z, b4.w};
        #pragma unroll
        for (int ii = 0; ii < 4; ++ii)
          #pragma unroll
          for (int jj = 0; jj < 4; ++jj)
            acc[ii][jj] = fmaf(a[ii], bb[jj], acc[ii][jj]);
      }
      __syncthreads();
    }
    // epilogue: score + top5 insert (registers + global xx only, no LDS hazard)
    float xg[4];
    #pragma unroll
    for (int jj = 0; jj < 4; ++jj) xg[jj] = xx[b * Nc + m0 + tx * 4 + jj];
    #pragma unroll
    for (int ii = 0; ii < 4; ++ii)
      #pragma unroll
      for (int jj = 0; jj < 4; ++jj)
        insert5(tv[ii], tix[ii], 2.f * acc[ii][jj] - xg[jj], m0 + tx * 4 + jj);
  }

  // merge across the 16 threads sharing each row; two halves of 32 rows
  float* sval = &As[0][0];        // 32*80 floats
  int*   sidx = (int*)&Bs[0][0];  // 32*80 ints
  for (int h = 0; h < 2; ++h) {
    __syncthreads();
    if ((ty >> 3) == h) {
      #pragma unroll
      for (int ii = 0; ii < 4; ++ii) {
        const int rl = (ty & 7) * 4 + ii;   // 0..31
        #pragma unroll
        for (int q = 0; q < 5; ++q) {
          sval[(rl * 16 + tx) * 5 + q] = tv[ii][q];
          sidx[(rl * 16 + tx) * 5 + q] = tix[ii][q];
        }
      }
    }
    __syncthreads();
    if (tid < 32) {
      float v[5]; int ix[5];
      #pragma unroll
      for (int q = 0; q < 5; ++q) { v[q] = -INFINITY; ix[q] = 0; }
      for (int c = 0; c < 80; ++c) insert5(v, ix, sval[tid * 80 + c], sidx[tid * 80 + c]);
      const int r = h * 32 + tid;
      const size_t base = ((size_t)(b * Nc + n0 + r) * 4 + mq) * 5;
      #pragma unroll
      for (int q = 0; q < 5; ++q) { pval[base + q] = v[q]; pidx[base + q] = ix[q]; }
    }
  }
}

// ---- merge 4 quarter-lists -> final top5 indices ----
__global__ __launch_bounds__(256) void k_knn_merge(const float* __restrict__ pval,
                                                   const int* __restrict__ pidx,
                                                   int* __restrict__ knn) {
  const int t = blockIdx.x * 256 + threadIdx.x;  // 0..16383
  const float* pv = pval + (size_t)t * 20;
  const int*   pi = pidx + (size_t)t * 20;
  float v[5]; int ix[5];
  #pragma unroll
  for (int q = 0; q < 5; ++q) { v[q] = -INFINITY; ix[q] = 0; }
  for (int c = 0; c < 20; ++c) insert5(v, ix, pv[c], pi[c]);
  #pragma unroll
  for (int q = 0; q < 5; ++q) knn[(size_t)t * 5 + q] = ix[q];
}

// ---- U = W1 @ X, V = (W2-W1) @ X, stored [b][n][o]. grid (64,4,8) ----
__global__ __launch_bounds__(256) void k_uv(const float* __restrict__ x,
                                            const float* __restrict__ W,
                                            float* __restrict__ U,
                                            float* __restrict__ V) {
  __shared__ float As[32][64];
  __shared__ float Bs[32][68];
  const int tid = threadIdx.x;
  const int tx = tid & 15, ty = tid >> 4;
  const int j0 = blockIdx.x * 64;
  const int o0 = blockIdx.y * 64;
  const int b  = blockIdx.z >> 1;
  const int uv = blockIdx.z & 1;
  const float* Xb = x + (size_t)b * Cc * Nc;
  float* out = (uv ? V : U) + (size_t)b * Nc * Cc;

  float acc[4][4];
  #pragma unroll
  for (int ii = 0; ii < 4; ++ii)
    #pragma unroll
    for (int jj = 0; jj < 4; ++jj) acc[ii][jj] = 0.f;

  const int i4 = (tid & 15) * 4;
  const int krow = tid >> 4;
  const int ow = tid >> 2;          // 0..63
  const int k8 = (tid & 3) * 8;

  for (int kc = 0; kc < 8; ++kc) {
    const int kb = kc * 32;
    *(float4*)&As[krow][i4]      = *(const float4*)(Xb + (size_t)(kb + krow) * Nc + j0 + i4);
    *(float4*)&As[krow + 16][i4] = *(const float4*)(Xb + (size_t)(kb + krow + 16) * Nc + j0 + i4);
    {
      const float* wr = W + (size_t)(o0 + ow) * 512 + kb + k8;
      #pragma unroll
      for (int i = 0; i < 8; ++i) {
        const float w1 = wr[i];
        Bs[k8 + i][ow] = uv ? (wr[256 + i] - w1) : w1;
      }
    }
    __syncthreads();
    #pragma unroll 4
    for (int kl = 0; kl < 32; ++kl) {
      const float4 a4 = *(const float4*)&As[kl][ty * 4];
      const float4 b4 = *(const float4*)&Bs[kl][tx * 4];
      const float a[4]  = {a4.x, a4.y, a4.z, a4.w};
      const float bb[4] = {b4.x, b4.y, b4.z, b4.w};
      #pragma unroll
      for (int ii = 0; ii < 4; ++ii)
        #pragma unroll
        for (int jj = 0; jj < 4; ++jj)
          acc[ii][jj] = fmaf(a[ii], bb[jj], acc[ii][jj]);
    }
    __syncthreads();
  }
  #pragma unroll
  for (int ii = 0; ii < 4; ++ii) {
    float4 vv = make_float4(acc[ii][0], acc[ii][1], acc[ii][2], acc[ii][3]);
    *(float4*)(out + (size_t)(j0 + ty * 4 + ii) * Cc + o0 + tx * 4) = vv;
  }
}

// ---- gather y = U[j]+V[n]; per-(b,n,o) max/min; per-o partial sums. grid (N,B) ----
__global__ __launch_bounds__(256) void k_gather(const float* __restrict__ U,
                                                const float* __restrict__ V,
                                                const int* __restrict__ knn,
                                                float* __restrict__ Mx,
                                                float* __restrict__ mn,
                                                float* __restrict__ p1,
                                                float* __restrict__ p2) {
  const int n = blockIdx.x, b = blockIdx.y, o = threadIdx.x;
  const size_t base = (size_t)b * Nc + n;
  const int* id = knn + base * 5;
  const float v = V[base * Cc + o];
  float M = -INFINITY, m = INFINITY, s1 = 0.f, s2 = 0.f;
  #pragma unroll
  for (int k = 0; k < 5; ++k) {
    const int j = id[k];
    const float y = U[((size_t)b * Nc + j) * Cc + o] + v;
    M = fmaxf(M, y); m = fminf(m, y);
    s1 += y; s2 += y * y;
  }
  Mx[base * Cc + o] = M;
  mn[base * Cc + o] = m;
  const int slot = n & 255;
  atomicAdd(&p1[(slot << 8) + o], s1);
  atomicAdd(&p2[(slot << 8) + o], s2);
}

// ---- finalize BN stats -> scale/shift ----
__global__ __launch_bounds__(256) void k_stats(const float* __restrict__ p1,
                                               const float* __restrict__ p2,
                                               const float* __restrict__ gamma,
                                               const float* __restrict__ beta,
                                               float* __restrict__ scsh) {
  const int o = threadIdx.x;
  float s1 = 0.f, s2 = 0.f;
  for (int c = 0; c < 256; ++c) { s1 += p1[(c << 8) + o]; s2 += p2[(c << 8) + o]; }
  const float inv_cnt = 1.0f / (float)(Bc * Nc * 5);
  const float mean = s1 * inv_cnt;
  const float var = s2 * inv_cnt - mean * mean;
  const float sc = gamma[o] * rsqrtf(var + 1e-5f);
  scsh[o] = sc;
  scsh[256 + o] = beta[o] - mean * sc;
}

// ---- apply BN/relu to max-or-min, transpose [b][n][o]->[b][o][n], +x. grid (64,4,4) ----
__global__ __launch_bounds__(256) void k_final(const float* __restrict__ Mx,
                                               const float* __restrict__ mn,
                                               const float* __restrict__ scsh,
                                               const float* __restrict__ x,
                                               float* __restrict__ out) {
  __shared__ float T[64][65];
  const int n0 = blockIdx.x * 64, o0 = blockIdx.y * 64, b = blockIdx.z;
  const int tid = threadIdx.x;
  #pragma unroll
  for (int it = 0; it < 16; ++it) {
    const int e = tid + 256 * it;
    const int i = e >> 6, j = e & 63;
    const int o = o0 + j;
    const float sc = scsh[o], sh = scsh[256 + o];
    const size_t idx = ((size_t)b * Nc + n0 + i) * Cc + o;
    const float val = (sc >= 0.f) ? Mx[idx] : mn[idx];
    T[i][j] = fmaxf(fmaf(sc, val, sh), 0.f);
  }
  __syncthreads();
  #pragma unroll
  for (int it = 0; it < 16; ++it) {
    const int e = tid + 256 * it;
    const int ol = e >> 6, nl = e & 63;
    const size_t idx = ((size_t)(b * Cc + o0 + ol)) * Nc + n0 + nl;
    out[idx] = T[nl][ol] + x[idx];
  }
}

extern "C" void kernel_launch(void* const* d_in, const int* in_sizes, int n_in,
                              void* d_out, int out_size, void* d_ws, size_t ws_size,
                              hipStream_t stream) {
  const float* x     = (const float*)d_in[0];
  const float* W     = (const float*)d_in[1];
  const float* gamma = (const float*)d_in[2];
  const float* beta  = (const float*)d_in[3];
  float* out = (float*)d_out;
  char*  ws  = (char*)d_ws;

  float* xx   = (float*)(ws + WS_XX);
  int*   knn  = (int*)  (ws + WS_KNN);
  float* U    = (float*)(ws + WS_U);
  float* V    = (float*)(ws + WS_V);
  float* Mx   = (float*)(ws + WS_MX);
  float* mn   = (float*)(ws + WS_MN);
  float* p1   = (float*)(ws + WS_P1);
  float* p2   = (float*)(ws + WS_P2);
  float* scsh = (float*)(ws + WS_SCSH);
  float* pval = (float*)(ws + WS_PVAL);
  int*   pidx = (int*)  (ws + WS_PIDX);

  // zero the per-o partial-sum accumulators (p1,p2 contiguous)
  hipMemsetAsync(p1, 0, 2 * 256 * 256 * sizeof(float), stream);

  k_xx      <<<256,               256, 0, stream>>>(x, xx);
  k_knn     <<<dim3(64, 4, 4),    256, 0, stream>>>(x, xx, pval, pidx);
  k_knn_merge<<<64,               256, 0, stream>>>(pval, pidx, knn);
  k_uv      <<<dim3(64, 4, 8),    256, 0, stream>>>(x, W, U, V);
  k_gather  <<<dim3(4096, 4),     256, 0, stream>>>(U, V, knn, Mx, mn, p1, p2);
  k_stats   <<<1,                 256, 0, stream>>>(p1, p2, gamma, beta, scsh);
  k_final   <<<dim3(64, 4, 4),    256, 0, stream>>>(Mx, mn, scsh, x, out);
}

// Round 2
// 486.287 us; speedup vs baseline: 1.6406x; 1.6406x over previous
//
#include <hip/hip_runtime.h>
#include <math.h>

// ResBlock (DGCNN edge-conv) — round 2: MFMA bf16 gram + top-8 candidates + exact
// fp32 rescore; MFMA U/V; two-pass BN apply (no Mx/mn buffers).
//
//   score s_m = 2<x_n,x_m> - xx[m]   (xx[n] row-constant, dropped)
//   y[b,o,n,k] = U[b,j_k,o] + V[b,n,o],  U = W1 @ X, V = (W2-W1) @ X
//   out = relu(sc*(sc>=0 ? max_k y : min_k y) + sh) + x
//
// KNN path: bf16 MFMA gram (fused per-row top-8 on fp16 scores, margin-safe)
//           -> merge -> exact fp32 rescore of 8 candidates -> top-5 set.
// B=4, C=256, N=4096, K=5.

#define Bc 4
#define Cc 256
#define Nc 4096

typedef short bf16x8 __attribute__((ext_vector_type(8)));
typedef float f32x4 __attribute__((ext_vector_type(4)));
typedef _Float16 f16x8 __attribute__((ext_vector_type(8)));

#define GLOBAL_AS __attribute__((address_space(1)))
#define LDS_AS __attribute__((address_space(3)))

__device__ __forceinline__ void gl_lds16(const void* g, void* l) {
  __builtin_amdgcn_global_load_lds((const GLOBAL_AS unsigned int*)g,
                                   (LDS_AS unsigned int*)l, 16, 0, 0);
}

__device__ __forceinline__ float bf2f(unsigned short u) {
  union { unsigned int i; float f; } x; x.i = ((unsigned int)u) << 16; return x.f;
}
__device__ __forceinline__ unsigned short f2bf(float f) {
  union { float f; unsigned int i; } x; x.f = f;
  unsigned int r = x.i + 0x7FFFu + ((x.i >> 16) & 1u);
  return (unsigned short)(r >> 16);
}

// caller guarantees s > v[7]; strictly-greater bubble keeps earlier (lower-m) on ties
__device__ __forceinline__ void insert8(float (&v)[8], int (&ix)[8], float s, int id) {
  v[7] = s; ix[7] = id;
  #pragma unroll
  for (int q = 7; q >= 1; --q) {
    if (v[q] > v[q - 1]) {
      float tv = v[q]; v[q] = v[q - 1]; v[q - 1] = tv;
      int ti = ix[q]; ix[q] = ix[q - 1]; ix[q - 1] = ti;
    }
  }
}

__device__ __forceinline__ void insert5(float (&v)[5], int (&ix)[5], float s, int id) {
  if (s <= v[4]) return;
  v[4] = s; ix[4] = id;
  #pragma unroll
  for (int q = 4; q >= 1; --q) {
    if (v[q] > v[q - 1]) {
      float tv = v[q]; v[q] = v[q - 1]; v[q - 1] = tv;
      int ti = ix[q]; ix[q] = ix[q - 1]; ix[q - 1] = ti;
    }
  }
}

// ---- workspace layout (bytes) ----
#define WS_XX    ((size_t)0)          //  65,536   xx[b][n] f32
#define WS_XTBF  ((size_t)65536)      //  8,388,608  XT bf16 [b][n][c]
#define WS_W1    ((size_t)8454144)    //  131,072  W1 bf16 [o][c]
#define WS_WD    ((size_t)8585216)    //  131,072  (W2-W1) bf16 [o][c]
#define WS_PLIST ((size_t)8716288)    //  16,777,216  partial top8 (row,mq,h,q)(v,i)
#define WS_CAND  ((size_t)25493504)   //  524,288  cand8 idx
#define WS_KNN   ((size_t)26017792)   //  327,680  knn5 idx
#define WS_XT32  ((size_t)26345472)   //  4,194,304  per-batch XT fp32 [n][c]
#define WS_U     ((size_t)30539776)   //  8,388,608  U bf16 [b][n][o]
#define WS_V     ((size_t)38928384)   //  8,388,608  V bf16 [b][n][o]
#define WS_P1    ((size_t)47316992)   //  262,144
#define WS_P2    ((size_t)47579136)   //  262,144
#define WS_SCSH  ((size_t)47841280)   //  2,048
// total ~47.8 MB (round-1's 69.7 MB fit, so this is safe)

// ---- xx[b,n] = sum_c x^2 ----
__global__ __launch_bounds__(256) void k_xx(const float* __restrict__ x,
                                            float* __restrict__ xx) {
  const int g0 = blockIdx.x * 64;
  const int b = g0 >> 12, n0 = g0 & 4095;
  const int nl = threadIdx.x & 63, cq = threadIdx.x >> 6;
  const float* p = x + ((size_t)(b * Cc + cq * 64)) * Nc + n0 + nl;
  float s = 0.f;
  #pragma unroll 8
  for (int c = 0; c < 64; ++c) { float v = p[(size_t)c * Nc]; s += v * v; }
  __shared__ float sh[4][64];
  sh[cq][nl] = s;
  __syncthreads();
  if (threadIdx.x < 64) {
    xx[g0 + threadIdx.x] = sh[0][threadIdx.x] + sh[1][threadIdx.x]
                         + sh[2][threadIdx.x] + sh[3][threadIdx.x];
  }
}

// ---- X [b][c][n] fp32 -> XTbf [b][n][c] bf16 (tiled transpose) ----
__global__ __launch_bounds__(256) void k_cvtbf(const float* __restrict__ x,
                                               unsigned short* __restrict__ xtbf) {
  __shared__ float T[64][65];
  const int t = threadIdx.x;
  const int n0 = blockIdx.x * 64, c0 = blockIdx.y * 64, b = blockIdx.z;
  #pragma unroll
  for (int it = 0; it < 4; ++it) {
    const int r = it * 16 + (t >> 4);
    const int col4 = (t & 15) * 4;
    float4 v = *(const float4*)(x + ((size_t)(b * Cc + c0 + r)) * Nc + n0 + col4);
    T[col4 + 0][r] = v.x; T[col4 + 1][r] = v.y; T[col4 + 2][r] = v.z; T[col4 + 3][r] = v.w;
  }
  __syncthreads();
  #pragma unroll
  for (int it = 0; it < 4; ++it) {
    const int nl = it * 16 + (t >> 4);
    const int c4 = (t & 15) * 4;
    ushort4 o;
    o.x = f2bf(T[nl][c4 + 0]); o.y = f2bf(T[nl][c4 + 1]);
    o.z = f2bf(T[nl][c4 + 2]); o.w = f2bf(T[nl][c4 + 3]);
    *(ushort4*)(xtbf + ((size_t)(b * Nc + n0 + nl)) * Cc + c0 + c4) = o;
  }
}

// ---- per-batch X -> XT32 [n][c] fp32 ----
__global__ __launch_bounds__(256) void k_t32(const float* __restrict__ xb,
                                             float* __restrict__ xt32) {
  __shared__ float T[64][65];
  const int t = threadIdx.x;
  const int n0 = blockIdx.x * 64, c0 = blockIdx.y * 64;
  #pragma unroll
  for (int it = 0; it < 4; ++it) {
    const int r = it * 16 + (t >> 4);
    const int col4 = (t & 15) * 4;
    float4 v = *(const float4*)(xb + ((size_t)(c0 + r)) * Nc + n0 + col4);
    T[col4 + 0][r] = v.x; T[col4 + 1][r] = v.y; T[col4 + 2][r] = v.z; T[col4 + 3][r] = v.w;
  }
  __syncthreads();
  #pragma unroll
  for (int it = 0; it < 4; ++it) {
    const int nl = it * 16 + (t >> 4);
    const int c4 = (t & 15) * 4;
    float4 o;
    o.x = T[nl][c4 + 0]; o.y = T[nl][c4 + 1]; o.z = T[nl][c4 + 2]; o.w = T[nl][c4 + 3];
    *(float4*)(xt32 + ((size_t)(n0 + nl)) * Cc + c0 + c4) = o;
  }
}

// ---- W fp32 [o][512] -> W1bf [o][256], Wdbf = (W2-W1) [o][256] bf16 ----
__global__ __launch_bounds__(256) void k_wcvt(const float* __restrict__ W,
                                              unsigned short* __restrict__ w1,
                                              unsigned short* __restrict__ wd) {
  const int o = blockIdx.x, c = threadIdx.x;
  const float a = W[(size_t)o * 512 + c];
  const float d = W[(size_t)o * 512 + 256 + c] - a;
  w1[(size_t)o * 256 + c] = f2bf(a);
  wd[(size_t)o * 256 + c] = f2bf(d);
}

// ---- MFMA gram + fused per-row top-8 (fp16 scores). grid (32 ntile, 8 mq, 4 b) ----
// LDS (dynamic 64KB): staging region; rows 512B, 16B chunks XOR-swizzled by (p ^ (r&31))
__global__ __launch_bounds__(256, 2) void k_gram(const unsigned short* __restrict__ Xbf,
                                                 const float* __restrict__ xx,
                                                 float2* __restrict__ plist) {
  extern __shared__ char smem[];
  const int tid = threadIdx.x, lane = tid & 63, w = tid >> 6;
  const int n0 = blockIdx.x * 128, mq = blockIdx.y, b = blockIdx.z;
  const unsigned short* Xb = Xbf + (size_t)b * Nc * Cc;
  const float* xxb = xx + b * Nc;

  // ---- stage A rows (n0..n0+127) chunk-wise; keep A-fragments in VGPRs ----
  bf16x8 afrag[4][8];
  #pragma unroll
  for (int ch = 0; ch < 2; ++ch) {
    __syncthreads();
    #pragma unroll
    for (int t = 0; t < 8; ++t) {
      const int instr = w * 8 + t;
      const int r = instr * 2 + (lane >> 5);
      const int p = (lane & 31) ^ (r & 31);
      gl_lds16(Xb + ((size_t)(n0 + ch * 64 + r)) * 256 + p * 8, smem + instr * 1024);
    }
    __syncthreads();
    if ((w >> 1) == ch) {   // wave-uniform branch
      #pragma unroll
      for (int i = 0; i < 4; ++i) {
        const int r = i * 16 + (lane & 15);
        #pragma unroll
        for (int ks = 0; ks < 8; ++ks) {
          const int p = ks * 4 + (lane >> 4);
          afrag[i][ks] = *(const bf16x8*)(smem + r * 512 + ((p ^ (r & 31)) * 16));
        }
      }
    }
  }

  float vl[8]; int il[8];
  #pragma unroll
  for (int q = 0; q < 8; ++q) { vl[q] = -INFINITY; il[q] = 0; }

  for (int mt = 0; mt < 4; ++mt) {
    const int m_base = mq * 512 + mt * 128;
    __syncthreads();
    // stage B rows (m_base..m_base+127): 64KB
    #pragma unroll
    for (int t = 0; t < 16; ++t) {
      const int instr = w * 16 + t;
      const int r = instr * 2 + (lane >> 5);
      const int p = (lane & 31) ^ (r & 31);
      gl_lds16(Xb + ((size_t)(m_base + r)) * 256 + p * 8, smem + instr * 1024);
    }
    __syncthreads();

    f32x4 acc[4][4];
    #pragma unroll
    for (int i = 0; i < 4; ++i)
      #pragma unroll
      for (int j = 0; j < 4; ++j) acc[i][j] = (f32x4){0.f, 0.f, 0.f, 0.f};

    #pragma unroll
    for (int ks = 0; ks < 8; ++ks) {
      bf16x8 bfr[4];
      #pragma unroll
      for (int j = 0; j < 4; ++j) {
        const int c = (w & 1) * 64 + j * 16 + (lane & 15);
        const int p = ks * 4 + (lane >> 4);
        bfr[j] = *(const bf16x8*)(smem + c * 512 + ((p ^ (c & 31)) * 16));
      }
      #pragma unroll
      for (int i = 0; i < 4; ++i)
        #pragma unroll
        for (int j = 0; j < 4; ++j)
          acc[i][j] = __builtin_amdgcn_mfma_f32_16x16x32_bf16(afrag[i][ks], bfr[j],
                                                              acc[i][j], 0, 0, 0);
    }
    __syncthreads();
    // stage scores t = g - 0.5*xx[m] as fp16 into S_lds [128][136] halves (272B rows)
    #pragma unroll
    for (int j = 0; j < 4; ++j) {
      const int colt = (w & 1) * 64 + j * 16 + (lane & 15);
      const float xxh = 0.5f * xxb[m_base + colt];
      #pragma unroll
      for (int i = 0; i < 4; ++i)
        #pragma unroll
        for (int rg = 0; rg < 4; ++rg) {
          const int rowt = (w >> 1) * 64 + i * 16 + (lane >> 4) * 4 + rg;
          *(_Float16*)(smem + rowt * 272 + colt * 2) = (_Float16)(acc[i][j][rg] - xxh);
        }
    }
    __syncthreads();
    // scan: 2 threads/row, 64 cols each, persistent top-8
    {
      const int r = tid & 127, h = tid >> 7;
      const char* srow = smem + r * 272 + h * 128;
      #pragma unroll
      for (int kk = 0; kk < 8; ++kk) {
        f16x8 v8 = *(const f16x8*)(srow + kk * 16);
        float f0 = (float)v8[0], f1 = (float)v8[1], f2 = (float)v8[2], f3 = (float)v8[3];
        float f4 = (float)v8[4], f5 = (float)v8[5], f6 = (float)v8[6], f7 = (float)v8[7];
        const float mx = fmaxf(fmaxf(fmaxf(f0, f1), fmaxf(f2, f3)),
                               fmaxf(fmaxf(f4, f5), fmaxf(f6, f7)));
        if (mx > vl[7]) {
          const int ibase = m_base + h * 64 + kk * 8;
          if (f0 > vl[7]) insert8(vl, il, f0, ibase + 0);
          if (f1 > vl[7]) insert8(vl, il, f1, ibase + 1);
          if (f2 > vl[7]) insert8(vl, il, f2, ibase + 2);
          if (f3 > vl[7]) insert8(vl, il, f3, ibase + 3);
          if (f4 > vl[7]) insert8(vl, il, f4, ibase + 4);
          if (f5 > vl[7]) insert8(vl, il, f5, ibase + 5);
          if (f6 > vl[7]) insert8(vl, il, f6, ibase + 6);
          if (f7 > vl[7]) insert8(vl, il, f7, ibase + 7);
        }
      }
    }
    __syncthreads();
  }
  // write partial lists: [row][mq][h][8] (val, idx-as-float)
  {
    const int rowg = b * Nc + n0 + (tid & 127);
    float2* pw = plist + ((size_t)rowg * 8 + mq) * 16 + (tid >> 7) * 8;
    #pragma unroll
    for (int q = 0; q < 8; ++q) pw[q] = make_float2(vl[q], __int_as_float(il[q]));
  }
}

// ---- merge 128 partial entries/row -> cand8 ----
__global__ __launch_bounds__(256) void k_cand(const float2* __restrict__ plist,
                                              int* __restrict__ cand8) {
  __shared__ float2 E[32][129];
  const int t = threadIdx.x;
  const int row0 = blockIdx.x * 32;
  #pragma unroll
  for (int it = 0; it < 16; ++it) {
    const int e = it * 256 + t;
    const int r = e >> 7, c = e & 127;
    E[r][c] = plist[(size_t)(row0 + r) * 128 + c];
  }
  __syncthreads();
  if (t < 32) {
    float v[8]; int ix[8];
    #pragma unroll
    for (int q = 0; q < 8; ++q) { v[q] = -INFINITY; ix[q] = 0; }
    for (int c = 0; c < 128; ++c) {
      const float2 p = E[t][c];
      if (p.x > v[7]) insert8(v, ix, p.x, __float_as_int(p.y));
    }
    #pragma unroll
    for (int q = 0; q < 8; ++q) cand8[(size_t)(row0 + t) * 8 + q] = ix[q];
  }
}

// ---- exact fp32 rescore of 8 candidates -> top-5 set (per batch) ----
__global__ __launch_bounds__(256) void k_rescore(const float* __restrict__ xt32,
                                                 const float* __restrict__ xxb,
                                                 const int* __restrict__ cand8b,
                                                 int* __restrict__ knnb) {
  const int lane = threadIdx.x & 63;
  const int row = blockIdx.x * 4 + (threadIdx.x >> 6);
  const int k = lane & 7, cchunk = lane >> 3;
  const int m = cand8b[(size_t)row * 8 + k];
  const float* srow = xt32 + (size_t)row * 256 + cchunk * 32;
  const float* crow = xt32 + (size_t)m * 256 + cchunk * 32;
  float dot = 0.f;
  #pragma unroll
  for (int q = 0; q < 8; ++q) {
    const float4 a = *(const float4*)(srow + q * 4);
    const float4 c = *(const float4*)(crow + q * 4);
    dot += a.x * c.x + a.y * c.y + a.z * c.z + a.w * c.w;
  }
  dot += __shfl_xor(dot, 8, 64);
  dot += __shfl_xor(dot, 16, 64);
  dot += __shfl_xor(dot, 32, 64);
  const float s = 2.f * dot - xxb[m];
  // rank among the 8 candidates (tie -> lower index first, like stable top_k)
  int rank = 0;
  #pragma unroll
  for (int j = 0; j < 8; ++j) {
    const float sj = __shfl(s, (lane & 56) + j, 64);
    const int mj = __shfl(m, (lane & 56) + j, 64);
    if (j != k && (sj > s || (sj == s && mj < m))) rank++;
  }
  if (cchunk == 0 && rank < 5) knnb[(size_t)row * 5 + rank] = m;
}

// ---- MFMA U/V: U = W1 @ X, V = (W2-W1) @ X, bf16 out [b][n][o]. grid (32,4,2) ----
__global__ __launch_bounds__(256, 2) void k_uv(const unsigned short* __restrict__ Xbf,
                                               const unsigned short* __restrict__ W1,
                                               const unsigned short* __restrict__ Wd,
                                               unsigned short* __restrict__ U,
                                               unsigned short* __restrict__ V) {
  extern __shared__ char smem[];
  const int tid = threadIdx.x, lane = tid & 63, w = tid >> 6;
  const int n0 = blockIdx.x * 128, b = blockIdx.y, uv = blockIdx.z;
  const unsigned short* Xb = Xbf + (size_t)b * Nc * Cc;
  const unsigned short* Wsel = uv ? Wd : W1;
  unsigned short* Osel = (uv ? V : U) + (size_t)b * Nc * Cc;

  bf16x8 afrag[4][8];
  #pragma unroll
  for (int ch = 0; ch < 2; ++ch) {
    __syncthreads();
    #pragma unroll
    for (int t = 0; t < 8; ++t) {
      const int instr = w * 8 + t;
      const int r = instr * 2 + (lane >> 5);
      const int p = (lane & 31) ^ (r & 31);
      gl_lds16(Xb + ((size_t)(n0 + ch * 64 + r)) * 256 + p * 8, smem + instr * 1024);
    }
    __syncthreads();
    if ((w >> 1) == ch) {
      #pragma unroll
      for (int i = 0; i < 4; ++i) {
        const int r = i * 16 + (lane & 15);
        #pragma unroll
        for (int ks = 0; ks < 8; ++ks) {
          const int p = ks * 4 + (lane >> 4);
          afrag[i][ks] = *(const bf16x8*)(smem + r * 512 + ((p ^ (r & 31)) * 16));
        }
      }
    }
  }

  for (int ot = 0; ot < 2; ++ot) {
    __syncthreads();
    #pragma unroll
    for (int t = 0; t < 16; ++t) {
      const int instr = w * 16 + t;
      const int r = instr * 2 + (lane >> 5);
      const int p = (lane & 31) ^ (r & 31);
      gl_lds16(Wsel + ((size_t)(ot * 128 + r)) * 256 + p * 8, smem + instr * 1024);
    }
    __syncthreads();

    f32x4 acc[4][4];
    #pragma unroll
    for (int i = 0; i < 4; ++i)
      #pragma unroll
      for (int j = 0; j < 4; ++j) acc[i][j] = (f32x4){0.f, 0.f, 0.f, 0.f};

    #pragma unroll
    for (int ks = 0; ks < 8; ++ks) {
      bf16x8 bfr[4];
      #pragma unroll
      for (int j = 0; j < 4; ++j) {
        const int c = (w & 1) * 64 + j * 16 + (lane & 15);
        const int p = ks * 4 + (lane >> 4);
        bfr[j] = *(const bf16x8*)(smem + c * 512 + ((p ^ (c & 31)) * 16));
      }
      #pragma unroll
      for (int i = 0; i < 4; ++i)
        #pragma unroll
        for (int j = 0; j < 4; ++j)
          acc[i][j] = __builtin_amdgcn_mfma_f32_16x16x32_bf16(afrag[i][ks], bfr[j],
                                                              acc[i][j], 0, 0, 0);
    }
    __syncthreads();
    // stage bf16 [128][136] ushort (272B rows), then coalesced copy-out
    #pragma unroll
    for (int j = 0; j < 4; ++j) {
      const int colt = (w & 1) * 64 + j * 16 + (lane & 15);
      #pragma unroll
      for (int i = 0; i < 4; ++i)
        #pragma unroll
        for (int rg = 0; rg < 4; ++rg) {
          const int rowt = (w >> 1) * 64 + i * 16 + (lane >> 4) * 4 + rg;
          *(unsigned short*)(smem + rowt * 272 + colt * 2) = f2bf(acc[i][j][rg]);
        }
    }
    __syncthreads();
    {
      const int r = tid >> 1, hf = tid & 1;
      #pragma unroll
      for (int kk = 0; kk < 8; ++kk) {
        const int4 d = *(const int4*)(smem + r * 272 + hf * 128 + kk * 16);
        *(int4*)((char*)Osel + ((size_t)(n0 + r) * 256 + ot * 128 + hf * 64 + kk * 8) * 2) = d;
      }
    }
    __syncthreads();
  }
}

// ---- BN stats pass: per-o sums of y over (n,k). grid (4096, 4) ----
__global__ __launch_bounds__(256) void k_stats1(const unsigned short* __restrict__ U,
                                                const unsigned short* __restrict__ V,
                                                const int* __restrict__ knn,
                                                float* __restrict__ p1,
                                                float* __restrict__ p2) {
  const int n = blockIdx.x, b = blockIdx.y, o = threadIdx.x;
  const size_t base = (size_t)b * Nc + n;
  __shared__ int ids[5];
  if (threadIdx.x < 5) ids[threadIdx.x] = knn[base * 5 + threadIdx.x];
  __syncthreads();
  const float v = bf2f(V[base * Cc + o]);
  float s1 = 0.f, s2 = 0.f;
  #pragma unroll
  for (int k = 0; k < 5; ++k) {
    const float y = bf2f(U[((size_t)b * Nc + ids[k]) * Cc + o]) + v;
    s1 += y; s2 += y * y;
  }
  atomicAdd(&p1[((n & 255) << 8) + o], s1);
  atomicAdd(&p2[((n & 255) << 8) + o], s2);
}

// ---- finalize BN stats -> scale/shift ----
__global__ __launch_bounds__(256) void k_stats(const float* __restrict__ p1,
                                               const float* __restrict__ p2,
                                               const float* __restrict__ gamma,
                                               const float* __restrict__ beta,
                                               float* __restrict__ scsh) {
  const int o = threadIdx.x;
  float s1 = 0.f, s2 = 0.f;
  for (int c = 0; c < 256; ++c) { s1 += p1[(c << 8) + o]; s2 += p2[(c << 8) + o]; }
  const float inv_cnt = 1.0f / (float)(Bc * Nc * 5);
  const float mean = s1 * inv_cnt;
  const float var = s2 * inv_cnt - mean * mean;
  const float sc = gamma[o] * rsqrtf(var + 1e-5f);
  scsh[o] = sc;
  scsh[256 + o] = beta[o] - mean * sc;
}

// ---- apply: recompute y extrema, BN+relu, transpose, +x. grid (128, 4) ----
__global__ __launch_bounds__(256) void k_apply(const unsigned short* __restrict__ U,
                                               const unsigned short* __restrict__ V,
                                               const int* __restrict__ knn,
                                               const float* __restrict__ scsh,
                                               const float* __restrict__ x,
                                               float* __restrict__ out) {
  __shared__ float T[32][257];
  __shared__ int ids[32][5];
  const int tid = threadIdx.x;
  const int n0 = blockIdx.x * 32, b = blockIdx.y;
  if (tid < 160) ids[tid / 5][tid % 5] = knn[((size_t)b * Nc + n0 + tid / 5) * 5 + tid % 5];
  __syncthreads();
  const int o = tid;
  const float sc = scsh[o], sh = scsh[256 + o];
  for (int nl = 0; nl < 32; ++nl) {
    const float v = bf2f(V[((size_t)b * Nc + n0 + nl) * Cc + o]);
    float M = -INFINITY, m = INFINITY;
    #pragma unroll
    for (int k = 0; k < 5; ++k) {
      const float y = bf2f(U[((size_t)b * Nc + ids[nl][k]) * Cc + o]) + v;
      M = fmaxf(M, y); m = fminf(m, y);
    }
    const float val = (sc >= 0.f) ? M : m;
    T[nl][o] = fmaxf(fmaf(sc, val, sh), 0.f);
  }
  __syncthreads();
  #pragma unroll
  for (int it = 0; it < 8; ++it) {
    const int q = tid + 256 * it;           // 2048 quads = 32n x 256o
    const int o2 = q >> 3, n4 = (q & 7) * 4;
    const size_t gi = ((size_t)(b * Cc + o2)) * Nc + n0 + n4;
    const float4 xv = *(const float4*)(x + gi);
    float4 r;
    r.x = T[n4 + 0][o2] + xv.x; r.y = T[n4 + 1][o2] + xv.y;
    r.z = T[n4 + 2][o2] + xv.z; r.w = T[n4 + 3][o2] + xv.w;
    *(float4*)(out + gi) = r;
  }
}

extern "C" void kernel_launch(void* const* d_in, const int* in_sizes, int n_in,
                              void* d_out, int out_size, void* d_ws, size_t ws_size,
                              hipStream_t stream) {
  const float* x     = (const float*)d_in[0];
  const float* W     = (const float*)d_in[1];
  const float* gamma = (const float*)d_in[2];
  const float* beta  = (const float*)d_in[3];
  float* out = (float*)d_out;
  char*  ws  = (char*)d_ws;

  float*          xx    = (float*)(ws + WS_XX);
  unsigned short* xtbf  = (unsigned short*)(ws + WS_XTBF);
  unsigned short* w1    = (unsigned short*)(ws + WS_W1);
  unsigned short* wd    = (unsigned short*)(ws + WS_WD);
  float2*         plist = (float2*)(ws + WS_PLIST);
  int*            cand8 = (int*)(ws + WS_CAND);
  int*            knn   = (int*)(ws + WS_KNN);
  float*          xt32  = (float*)(ws + WS_XT32);
  unsigned short* U     = (unsigned short*)(ws + WS_U);
  unsigned short* V     = (unsigned short*)(ws + WS_V);
  float*          p1    = (float*)(ws + WS_P1);
  float*          p2    = (float*)(ws + WS_P2);
  float*          scsh  = (float*)(ws + WS_SCSH);

  hipMemsetAsync(p1, 0, 2 * 256 * 256 * sizeof(float), stream);

  k_xx    <<<256,              256, 0, stream>>>(x, xx);
  k_cvtbf <<<dim3(64, 4, 4),   256, 0, stream>>>(x, xtbf);
  k_wcvt  <<<256,              256, 0, stream>>>(W, w1, wd);
  k_gram  <<<dim3(32, 8, 4),   256, 65536, stream>>>(xtbf, xx, plist);
  k_cand  <<<512,              256, 0, stream>>>(plist, cand8);
  for (int b = 0; b < 4; ++b) {
    k_t32     <<<dim3(64, 4), 256, 0, stream>>>(x + (size_t)b * Cc * Nc, xt32);
    k_rescore <<<1024,        256, 0, stream>>>(xt32, xx + b * Nc,
                                                cand8 + (size_t)b * Nc * 8,
                                                knn + (size_t)b * Nc * 5);
  }
  k_uv     <<<dim3(32, 4, 2),  256, 65536, stream>>>(xtbf, w1, wd, U, V);
  k_stats1 <<<dim3(4096, 4),   256, 0, stream>>>(U, V, knn, p1, p2);
  k_stats  <<<1,               256, 0, stream>>>(p1, p2, gamma, beta, scsh);
  k_apply  <<<dim3(128, 4),    256, 0, stream>>>(U, V, knn, scsh, x, out);
}

// Round 4
// 396.805 us; speedup vs baseline: 2.0106x; 1.2255x over previous
//
#include <hip/hip_runtime.h>
#include <math.h>

// ResBlock (DGCNN edge-conv) — round 4: fp8 gram + top-16 candidates (was 8;
// fp8 score noise sigma~1.6 vs rank5->9 gap ~9 caused ~1 missed neighbor/run)
// + exact fp32 rescore of 16. U/V unchanged from round 3.
//   score s_m = 2<x_n,x_m> - xx[m]; y = U[j]+V[n]; out = relu(sc*ext + sh) + x
// B=4, C=256, N=4096, K=5.

#define Bc 4
#define Cc 256
#define Nc 4096

typedef short bf16x8 __attribute__((ext_vector_type(8)));
typedef float f32x16 __attribute__((ext_vector_type(16)));
typedef _Float16 f16x8 __attribute__((ext_vector_type(8)));

union U128 { int4 i; long2 l; bf16x8 s; };

#define GLOBAL_AS __attribute__((address_space(1)))
#define LDS_AS __attribute__((address_space(3)))

__device__ __forceinline__ void gl_lds16(const void* g, void* l) {
  __builtin_amdgcn_global_load_lds((const GLOBAL_AS unsigned int*)g,
                                   (LDS_AS unsigned int*)l, 16, 0, 0);
}

__device__ __forceinline__ float bf2f(unsigned short u) {
  union { unsigned int i; float f; } x; x.i = ((unsigned int)u) << 16; return x.f;
}
__device__ __forceinline__ unsigned short f2bf(float f) {
  union { float f; unsigned int i; } x; x.f = f;
  unsigned int r = x.i + 0x7FFFu + ((x.i >> 16) & 1u);
  return (unsigned short)(r >> 16);
}

// caller guarantees s > v[7]
__device__ __forceinline__ void insert8(float (&v)[8], int (&ix)[8], float s, int id) {
  v[7] = s; ix[7] = id;
  #pragma unroll
  for (int q = 7; q >= 1; --q) {
    if (v[q] > v[q - 1]) {
      float tv = v[q]; v[q] = v[q - 1]; v[q - 1] = tv;
      int ti = ix[q]; ix[q] = ix[q - 1]; ix[q - 1] = ti;
    }
  }
}

// caller guarantees s > v[15]
__device__ __forceinline__ void insert16(float (&v)[16], int (&ix)[16], float s, int id) {
  v[15] = s; ix[15] = id;
  #pragma unroll
  for (int q = 15; q >= 1; --q) {
    if (v[q] > v[q - 1]) {
      float tv = v[q]; v[q] = v[q - 1]; v[q - 1] = tv;
      int ti = ix[q]; ix[q] = ix[q - 1]; ix[q - 1] = ti;
    }
  }
}

// ---- workspace layout (bytes) ----
#define WS_XX    ((size_t)0)          // 65,536
#define WS_P1    ((size_t)65536)      // 262,144
#define WS_P2    ((size_t)327680)     // 262,144   (memset covers XX..P2: 589,824)
#define WS_XF8   ((size_t)589824)     // 4,194,304   fp8 [b][n][c]
#define WS_XTBF  ((size_t)4784128)    // 8,388,608   bf16 [b][n][c]
#define WS_XT32  ((size_t)13172736)   // 16,777,216  fp32 [b][n][c]
#define WS_W1    ((size_t)29949952)   // 131,072
#define WS_WD    ((size_t)30081024)   // 131,072
#define WS_PLIST ((size_t)30212096)   // 16,777,216
#define WS_CAND  ((size_t)46989312)   // 1,048,576  cand16
#define WS_KNN   ((size_t)48037888)   // 327,680
#define WS_U     ((size_t)48365568)   // 8,388,608   bf16 [b][n][o]
#define WS_V     ((size_t)56754176)   // 8,388,608
#define WS_SCSH  ((size_t)65142784)   // 2,048
// total ~65.1 MB (round-1's 69.7 MB fit, so safe)

// ---- fused transpose: x [b][c][n] f32 -> xtbf/xf8/xt32 [b][n][c] + xx ----
__global__ __launch_bounds__(256) void k_prep(const float* __restrict__ x,
                                              unsigned short* __restrict__ xtbf,
                                              unsigned char* __restrict__ xf8,
                                              float* __restrict__ xt32,
                                              float* __restrict__ xx) {
  __shared__ float T[64][65];
  __shared__ float ps[64][17];
  const int t = threadIdx.x;
  const int n0 = blockIdx.x * 64, c0 = blockIdx.y * 64, b = blockIdx.z;
  #pragma unroll
  for (int it = 0; it < 4; ++it) {
    const int r = it * 16 + (t >> 4);
    const int col4 = (t & 15) * 4;
    float4 v = *(const float4*)(x + ((size_t)(b * Cc + c0 + r)) * Nc + n0 + col4);
    T[col4 + 0][r] = v.x; T[col4 + 1][r] = v.y; T[col4 + 2][r] = v.z; T[col4 + 3][r] = v.w;
  }
  __syncthreads();
  #pragma unroll
  for (int it = 0; it < 4; ++it) {
    const int nl = it * 16 + (t >> 4);
    const int c4 = (t & 15) * 4;
    const float a = T[nl][c4 + 0], bb = T[nl][c4 + 1];
    const float c = T[nl][c4 + 2], d = T[nl][c4 + 3];
    const size_t base = ((size_t)(b * Nc + n0 + nl)) * Cc + c0 + c4;
    ushort4 o; o.x = f2bf(a); o.y = f2bf(bb); o.z = f2bf(c); o.w = f2bf(d);
    *(ushort4*)(xtbf + base) = o;
    float4 f; f.x = a; f.y = bb; f.z = c; f.w = d;
    *(float4*)(xt32 + base) = f;
    int pk = 0;
    pk = __builtin_amdgcn_cvt_pk_fp8_f32(a, bb, pk, false);
    pk = __builtin_amdgcn_cvt_pk_fp8_f32(c, d, pk, true);
    *(int*)(xf8 + base) = pk;
    ps[nl][t & 15] = a * a + bb * bb + c * c + d * d;
  }
  __syncthreads();
  if (t < 64) {
    float tot = 0.f;
    #pragma unroll
    for (int g = 0; g < 16; ++g) tot += ps[t][g];
    atomicAdd(&xx[b * Nc + n0 + t], tot);
  }
}

// ---- W fp32 [o][512] -> W1bf [o][256], Wdbf=(W2-W1) bf16 ----
__global__ __launch_bounds__(256) void k_wcvt(const float* __restrict__ W,
                                              unsigned short* __restrict__ w1,
                                              unsigned short* __restrict__ wd) {
  const int o = blockIdx.x, c = threadIdx.x;
  const float a = W[(size_t)o * 512 + c];
  const float d = W[(size_t)o * 512 + 256 + c] - a;
  w1[(size_t)o * 256 + c] = f2bf(a);
  wd[(size_t)o * 256 + c] = f2bf(d);
}

// ---- fp8 MFMA gram + fused per-row top-8. grid (32 ntile, 8 mq, 4 b) ----
// LDS 34816B: B tile 32KB (16B chunks swizzled p^(r&15)); scores [128][136] f16 overlay
__global__ __launch_bounds__(256, 1) void k_gram(const unsigned char* __restrict__ Xf8,
                                                 const float* __restrict__ xx,
                                                 float2* __restrict__ plist) {
  extern __shared__ char smem[];
  const int tid = threadIdx.x, lane = tid & 63, w = tid >> 6;
  const int n0 = blockIdx.x * 128, mq = blockIdx.y, b = blockIdx.z;
  const unsigned char* Xb = Xf8 + (size_t)b * Nc * Cc;
  const float* xxb = xx + b * Nc;
  const int h = w >> 1, mh = w & 1;

  // stage A tile (128 rows x 256 B) then pull A-fragments into VGPRs
  #pragma unroll
  for (int t = 0; t < 8; ++t) {
    const int instr = w * 8 + t;
    const int r = instr * 4 + (lane >> 4);
    const int p = (lane & 15) ^ (r & 15);
    gl_lds16(Xb + (size_t)(n0 + r) * 256 + p * 16, smem + instr * 1024);
  }
  __syncthreads();
  U128 afrag[2][8];
  #pragma unroll
  for (int it = 0; it < 2; ++it) {
    const int r = h * 64 + it * 32 + (lane & 31);
    #pragma unroll
    for (int kp = 0; kp < 8; ++kp) {
      const int p = kp * 2 + (lane >> 5);
      afrag[it][kp].i = *(const int4*)(smem + r * 256 + ((p ^ (r & 15)) * 16));
    }
  }

  float vl[8]; int il[8];
  #pragma unroll
  for (int q = 0; q < 8; ++q) { vl[q] = -INFINITY; il[q] = 0; }

  for (int mt = 0; mt < 4; ++mt) {
    const int m_base = mq * 512 + mt * 128;
    __syncthreads();
    #pragma unroll
    for (int t = 0; t < 8; ++t) {
      const int instr = w * 8 + t;
      const int r = instr * 4 + (lane >> 4);
      const int p = (lane & 15) ^ (r & 15);
      gl_lds16(Xb + (size_t)(m_base + r) * 256 + p * 16, smem + instr * 1024);
    }
    __syncthreads();

    f32x16 acc[2][2];
    #pragma unroll
    for (int i = 0; i < 2; ++i)
      #pragma unroll
      for (int j = 0; j < 2; ++j)
        acc[i][j] = (f32x16){0.f,0.f,0.f,0.f,0.f,0.f,0.f,0.f,
                             0.f,0.f,0.f,0.f,0.f,0.f,0.f,0.f};

    #pragma unroll
    for (int kp = 0; kp < 8; ++kp) {
      U128 bfr[2];
      #pragma unroll
      for (int jt = 0; jt < 2; ++jt) {
        const int m = mh * 64 + jt * 32 + (lane & 31);
        const int p = kp * 2 + (lane >> 5);
        bfr[jt].i = *(const int4*)(smem + m * 256 + ((p ^ (m & 15)) * 16));
      }
      #pragma unroll
      for (int it = 0; it < 2; ++it)
        #pragma unroll
        for (int jt = 0; jt < 2; ++jt) {
          acc[it][jt] = __builtin_amdgcn_mfma_f32_32x32x16_fp8_fp8(
              afrag[it][kp].l.x, bfr[jt].l.x, acc[it][jt], 0, 0, 0);
          acc[it][jt] = __builtin_amdgcn_mfma_f32_32x32x16_fp8_fp8(
              afrag[it][kp].l.y, bfr[jt].l.y, acc[it][jt], 0, 0, 0);
        }
    }
    __syncthreads();
    // scores t = g - 0.5*xx[m] as fp16 into [128][136] (272B rows)
    #pragma unroll
    for (int jt = 0; jt < 2; ++jt) {
      const int mcol = mh * 64 + jt * 32 + (lane & 31);
      const float xxh = 0.5f * xxb[m_base + mcol];
      #pragma unroll
      for (int it = 0; it < 2; ++it)
        #pragma unroll
        for (int v = 0; v < 16; ++v) {
          const int nrow = h * 64 + it * 32 + (v & 3) + 8 * (v >> 2) + 4 * (lane >> 5);
          *(_Float16*)(smem + nrow * 272 + mcol * 2) = (_Float16)(acc[it][jt][v] - xxh);
        }
    }
    __syncthreads();
    // scan: 2 threads/row, 64 cols each, persistent top-8
    {
      const int r = tid & 127, hh = tid >> 7;
      const char* srow = smem + r * 272 + hh * 128;
      #pragma unroll
      for (int kk = 0; kk < 8; ++kk) {
        f16x8 v8 = *(const f16x8*)(srow + kk * 16);
        float f0 = (float)v8[0], f1 = (float)v8[1], f2 = (float)v8[2], f3 = (float)v8[3];
        float f4 = (float)v8[4], f5 = (float)v8[5], f6 = (float)v8[6], f7 = (float)v8[7];
        const float mx = fmaxf(fmaxf(fmaxf(f0, f1), fmaxf(f2, f3)),
                               fmaxf(fmaxf(f4, f5), fmaxf(f6, f7)));
        if (mx > vl[7]) {
          const int ibase = m_base + hh * 64 + kk * 8;
          if (f0 > vl[7]) insert8(vl, il, f0, ibase + 0);
          if (f1 > vl[7]) insert8(vl, il, f1, ibase + 1);
          if (f2 > vl[7]) insert8(vl, il, f2, ibase + 2);
          if (f3 > vl[7]) insert8(vl, il, f3, ibase + 3);
          if (f4 > vl[7]) insert8(vl, il, f4, ibase + 4);
          if (f5 > vl[7]) insert8(vl, il, f5, ibase + 5);
          if (f6 > vl[7]) insert8(vl, il, f6, ibase + 6);
          if (f7 > vl[7]) insert8(vl, il, f7, ibase + 7);
        }
      }
    }
  }
  // partial lists: [row][mq][h][8]
  {
    const int rowg = b * Nc + n0 + (tid & 127);
    float2* pw = plist + ((size_t)rowg * 8 + mq) * 16 + (tid >> 7) * 8;
    #pragma unroll
    for (int q = 0; q < 8; ++q) pw[q] = make_float2(vl[q], __int_as_float(il[q]));
  }
}

// ---- merge 128 partial entries/row -> cand16 ----
__global__ __launch_bounds__(256) void k_cand(const float2* __restrict__ plist,
                                              int* __restrict__ cand16) {
  __shared__ float2 E[32][129];
  const int t = threadIdx.x;
  const int row0 = blockIdx.x * 32;
  #pragma unroll
  for (int it = 0; it < 16; ++it) {
    const int e = it * 256 + t;
    const int r = e >> 7, c = e & 127;
    E[r][c] = plist[(size_t)(row0 + r) * 128 + c];
  }
  __syncthreads();
  if (t < 32) {
    float v[16]; int ix[16];
    #pragma unroll
    for (int q = 0; q < 16; ++q) { v[q] = -INFINITY; ix[q] = 0; }
    for (int c = 0; c < 128; ++c) {
      const float2 p = E[t][c];
      if (p.x > v[15]) insert16(v, ix, p.x, __float_as_int(p.y));
    }
    #pragma unroll
    for (int q = 0; q < 16; ++q) cand16[(size_t)(row0 + t) * 16 + q] = ix[q];
  }
}

// ---- exact fp32 rescore of 16 candidates -> top-5 set. grid (1024, 4) ----
__global__ __launch_bounds__(256) void k_rescore(const float* __restrict__ xt32,
                                                 const float* __restrict__ xx,
                                                 const int* __restrict__ cand16,
                                                 int* __restrict__ knn) {
  const int b = blockIdx.y;
  const float* xb = xt32 + (size_t)b * Nc * Cc;
  const float* xxb = xx + b * Nc;
  const int lane = threadIdx.x & 63;
  const int row = blockIdx.x * 4 + (threadIdx.x >> 6);
  const int k = lane & 15, cchunk = lane >> 4;   // 16 cands x 4 chunks of 64 ch
  const int m = cand16[((size_t)b * Nc + row) * 16 + k];
  const float* srow = xb + (size_t)row * Cc + cchunk * 64;
  const float* crow = xb + (size_t)m * Cc + cchunk * 64;
  float dot = 0.f;
  #pragma unroll
  for (int q = 0; q < 16; ++q) {
    const float4 a = *(const float4*)(srow + q * 4);
    const float4 c = *(const float4*)(crow + q * 4);
    dot += a.x * c.x + a.y * c.y + a.z * c.z + a.w * c.w;
  }
  dot += __shfl_xor(dot, 16, 64);
  dot += __shfl_xor(dot, 32, 64);
  const float s = 2.f * dot - xxb[m];
  int rank = 0;
  #pragma unroll
  for (int j = 0; j < 16; ++j) {
    const float sj = __shfl(s, (lane & 48) + j, 64);
    const int mj = __shfl(m, (lane & 48) + j, 64);
    if (j != k && (sj > s || (sj == s && mj < m))) rank++;
  }
  if (cchunk == 0 && rank < 5)
    knn[((size_t)b * Nc + row) * 5 + rank] = m;
}

// ---- bf16 MFMA U/V, A-frags resident. grid (32 ntile, 4 b, 2 uv). LDS 64KB ----
__global__ __launch_bounds__(256, 1) void k_uv(const unsigned short* __restrict__ Xbf,
                                               const unsigned short* __restrict__ W1,
                                               const unsigned short* __restrict__ Wd,
                                               unsigned short* __restrict__ U,
                                               unsigned short* __restrict__ V) {
  extern __shared__ char smem[];
  const int tid = threadIdx.x, lane = tid & 63, w = tid >> 6;
  const int n0 = blockIdx.x * 128, b = blockIdx.y, uv = blockIdx.z;
  const unsigned short* Xb = Xbf + (size_t)b * Nc * Cc;
  const unsigned short* Wsel = uv ? Wd : W1;
  unsigned short* Osel = (uv ? V : U) + (size_t)b * Nc * Cc;
  const int h = w >> 1, mh = w & 1;

  // stage A (128 rows x 512 B bf16), pull fragments
  #pragma unroll
  for (int t = 0; t < 16; ++t) {
    const int instr = w * 16 + t;
    const int r = instr * 2 + (lane >> 5);
    const int p = (lane & 31) ^ (r & 31);
    gl_lds16(Xb + (size_t)(n0 + r) * 256 + p * 8, smem + instr * 1024);
  }
  __syncthreads();
  U128 afrag[2][16];
  #pragma unroll
  for (int it = 0; it < 2; ++it) {
    const int r = h * 64 + it * 32 + (lane & 31);
    #pragma unroll
    for (int ks = 0; ks < 16; ++ks) {
      const int p = ks * 2 + (lane >> 5);
      afrag[it][ks].i = *(const int4*)(smem + r * 512 + ((p ^ (r & 31)) * 16));
    }
  }

  for (int ot = 0; ot < 2; ++ot) {
    __syncthreads();
    #pragma unroll
    for (int t = 0; t < 16; ++t) {
      const int instr = w * 16 + t;
      const int r = instr * 2 + (lane >> 5);
      const int p = (lane & 31) ^ (r & 31);
      gl_lds16(Wsel + (size_t)(ot * 128 + r) * 256 + p * 8, smem + instr * 1024);
    }
    __syncthreads();

    f32x16 acc[2][2];
    #pragma unroll
    for (int i = 0; i < 2; ++i)
      #pragma unroll
      for (int j = 0; j < 2; ++j)
        acc[i][j] = (f32x16){0.f,0.f,0.f,0.f,0.f,0.f,0.f,0.f,
                             0.f,0.f,0.f,0.f,0.f,0.f,0.f,0.f};

    #pragma unroll
    for (int ks = 0; ks < 16; ++ks) {
      U128 bfr[2];
      #pragma unroll
      for (int jt = 0; jt < 2; ++jt) {
        const int o = mh * 64 + jt * 32 + (lane & 31);
        const int p = ks * 2 + (lane >> 5);
        bfr[jt].i = *(const int4*)(smem + o * 512 + ((p ^ (o & 31)) * 16));
      }
      #pragma unroll
      for (int it = 0; it < 2; ++it)
        #pragma unroll
        for (int jt = 0; jt < 2; ++jt)
          acc[it][jt] = __builtin_amdgcn_mfma_f32_32x32x16_bf16(
              afrag[it][ks].s, bfr[jt].s, acc[it][jt], 0, 0, 0);
    }
    __syncthreads();
    // stage bf16 [128][136] (272B rows)
    #pragma unroll
    for (int jt = 0; jt < 2; ++jt) {
      const int ocol = mh * 64 + jt * 32 + (lane & 31);
      #pragma unroll
      for (int it = 0; it < 2; ++it)
        #pragma unroll
        for (int v = 0; v < 16; ++v) {
          const int nrow = h * 64 + it * 32 + (v & 3) + 8 * (v >> 2) + 4 * (lane >> 5);
          *(unsigned short*)(smem + nrow * 272 + ocol * 2) = f2bf(acc[it][jt][v]);
        }
    }
    __syncthreads();
    {
      const int r = tid >> 1, hf = tid & 1;
      #pragma unroll
      for (int kk = 0; kk < 8; ++kk) {
        const int4 d = *(const int4*)(smem + r * 272 + hf * 128 + kk * 16);
        *(int4*)(Osel + (size_t)(n0 + r) * 256 + ot * 128 + hf * 64 + kk * 8) = d;
      }
    }
  }
}

// ---- BN sums over gathered y. grid (512, 4), 8 rows/block ----
__global__ __launch_bounds__(256) void k_stats1(const unsigned short* __restrict__ U,
                                                const unsigned short* __restrict__ V,
                                                const int* __restrict__ knn,
                                                float* __restrict__ p1,
                                                float* __restrict__ p2) {
  const int n0 = blockIdx.x * 8, b = blockIdx.y, o = threadIdx.x;
  __shared__ int ids[8][5];
  if (threadIdx.x < 40)
    ids[threadIdx.x / 5][threadIdx.x % 5] =
        knn[((size_t)b * Nc + n0 + threadIdx.x / 5) * 5 + threadIdx.x % 5];
  __syncthreads();
  float s1 = 0.f, s2 = 0.f;
  for (int r = 0; r < 8; ++r) {
    const float v = bf2f(V[((size_t)b * Nc + n0 + r) * Cc + o]);
    #pragma unroll
    for (int k = 0; k < 5; ++k) {
      const float y = bf2f(U[((size_t)b * Nc + ids[r][k]) * Cc + o]) + v;
      s1 += y; s2 += y * y;
    }
  }
  const int slot = blockIdx.x & 255;
  atomicAdd(&p1[(slot << 8) + o], s1);
  atomicAdd(&p2[(slot << 8) + o], s2);
}

// ---- finalize BN stats -> scale/shift ----
__global__ __launch_bounds__(256) void k_stats(const float* __restrict__ p1,
                                               const float* __restrict__ p2,
                                               const float* __restrict__ gamma,
                                               const float* __restrict__ beta,
                                               float* __restrict__ scsh) {
  const int o = threadIdx.x;
  float s1 = 0.f, s2 = 0.f;
  for (int c = 0; c < 256; ++c) { s1 += p1[(c << 8) + o]; s2 += p2[(c << 8) + o]; }
  const float inv_cnt = 1.0f / (float)(Bc * Nc * 5);
  const float mean = s1 * inv_cnt;
  const float var = s2 * inv_cnt - mean * mean;
  const float sc = gamma[o] * rsqrtf(var + 1e-5f);
  scsh[o] = sc;
  scsh[256 + o] = beta[o] - mean * sc;
}

// ---- apply: extrema, BN+relu, transpose, +x. grid (128, 4) ----
__global__ __launch_bounds__(256) void k_apply(const unsigned short* __restrict__ U,
                                               const unsigned short* __restrict__ V,
                                               const int* __restrict__ knn,
                                               const float* __restrict__ scsh,
                                               const float* __restrict__ x,
                                               float* __restrict__ out) {
  __shared__ float T[32][257];
  __shared__ int ids[32][5];
  const int tid = threadIdx.x;
  const int n0 = blockIdx.x * 32, b = blockIdx.y;
  if (tid < 160) ids[tid / 5][tid % 5] = knn[((size_t)b * Nc + n0 + tid / 5) * 5 + tid % 5];
  __syncthreads();
  const int o = tid;
  const float sc = scsh[o], sh = scsh[256 + o];
  for (int nl = 0; nl < 32; ++nl) {
    const float v = bf2f(V[((size_t)b * Nc + n0 + nl) * Cc + o]);
    float M = -INFINITY, m = INFINITY;
    #pragma unroll
    for (int k = 0; k < 5; ++k) {
      const float y = bf2f(U[((size_t)b * Nc + ids[nl][k]) * Cc + o]) + v;
      M = fmaxf(M, y); m = fminf(m, y);
    }
    const float val = (sc >= 0.f) ? M : m;
    T[nl][o] = fmaxf(fmaf(sc, val, sh), 0.f);
  }
  __syncthreads();
  #pragma unroll
  for (int it = 0; it < 8; ++it) {
    const int q = tid + 256 * it;
    const int o2 = q >> 3, n4 = (q & 7) * 4;
    const size_t gi = ((size_t)(b * Cc + o2)) * Nc + n0 + n4;
    const float4 xv = *(const float4*)(x + gi);
    float4 r;
    r.x = T[n4 + 0][o2] + xv.x; r.y = T[n4 + 1][o2] + xv.y;
    r.z = T[n4 + 2][o2] + xv.z; r.w = T[n4 + 3][o2] + xv.w;
    *(float4*)(out + gi) = r;
  }
}

extern "C" void kernel_launch(void* const* d_in, const int* in_sizes, int n_in,
                              void* d_out, int out_size, void* d_ws, size_t ws_size,
                              hipStream_t stream) {
  const float* x     = (const float*)d_in[0];
  const float* W     = (const float*)d_in[1];
  const float* gamma = (const float*)d_in[2];
  const float* beta  = (const float*)d_in[3];
  float* out = (float*)d_out;
  char*  ws  = (char*)d_ws;

  float*          xx     = (float*)(ws + WS_XX);
  float*          p1     = (float*)(ws + WS_P1);
  float*          p2     = (float*)(ws + WS_P2);
  unsigned char*  xf8    = (unsigned char*)(ws + WS_XF8);
  unsigned short* xtbf   = (unsigned short*)(ws + WS_XTBF);
  float*          xt32   = (float*)(ws + WS_XT32);
  unsigned short* w1     = (unsigned short*)(ws + WS_W1);
  unsigned short* wd     = (unsigned short*)(ws + WS_WD);
  float2*         plist  = (float2*)(ws + WS_PLIST);
  int*            cand16 = (int*)(ws + WS_CAND);
  int*            knn    = (int*)(ws + WS_KNN);
  unsigned short* U      = (unsigned short*)(ws + WS_U);
  unsigned short* V      = (unsigned short*)(ws + WS_V);
  float*          scsh   = (float*)(ws + WS_SCSH);

  hipMemsetAsync(ws + WS_XX, 0, 589824, stream);

  k_prep    <<<dim3(64, 4, 4),  256, 0, stream>>>(x, xtbf, xf8, xt32, xx);
  k_wcvt    <<<256,             256, 0, stream>>>(W, w1, wd);
  k_gram    <<<dim3(32, 8, 4),  256, 34816, stream>>>(xf8, xx, plist);
  k_cand    <<<512,             256, 0, stream>>>(plist, cand16);
  k_rescore <<<dim3(1024, 4),   256, 0, stream>>>(xt32, xx, cand16, knn);
  k_uv      <<<dim3(32, 4, 2),  256, 65536, stream>>>(xtbf, w1, wd, U, V);
  k_stats1  <<<dim3(512, 4),    256, 0, stream>>>(U, V, knn, p1, p2);
  k_stats   <<<1,               256, 0, stream>>>(p1, p2, gamma, beta, scsh);
  k_apply   <<<dim3(128, 4),    256, 0, stream>>>(U, V, knn, scsh, x, out);
}